// Round 3
// baseline (1661.516 us; speedup 1.0000x reference)
//
#include <hip/hip_runtime.h>
#include <hip/hip_bf16.h>

#define NN 100000
#define NE 1600000
#define NBN 5000
#define NCOARSE 512

// ---- ordered-uint encoding for float atomic min/max ----
__device__ __forceinline__ unsigned f2ord(float f) {
    unsigned u = __float_as_uint(f);
    return (u & 0x80000000u) ? ~u : (u | 0x80000000u);
}
__device__ __forceinline__ float ord2f(unsigned u) {
    u = (u & 0x80000000u) ? (u & 0x7FFFFFFFu) : ~u;
    return __uint_as_float(u);
}
__device__ __forceinline__ float lrelu(float x) { return x > 0.f ? x : 0.01f * x; }

// ---- mark boundary nodes ----
__global__ __launch_bounds__(256) void k_scatter(const int* __restrict__ bn, unsigned char* __restrict__ isb) {
    int i = blockIdx.x * 256 + threadIdx.x;
    if (i < NBN) isb[bn[i]] = 1;
}

// ---- embed: x = nodes_mod @ eW + eb  (wave per node, lane = feature) ----
__global__ __launch_bounds__(256) void k_embed(const float* __restrict__ nodes, const unsigned char* __restrict__ isb,
                                               const float* __restrict__ dmean, const float* __restrict__ dstd,
                                               const float* __restrict__ eW, const float* __restrict__ eb,
                                               float* __restrict__ x) {
    __shared__ float sW[448];
    __shared__ float sb[64];
    __shared__ float sm[3], sd[3];
    int t = threadIdx.x;
    for (int i = t; i < 448; i += 256) sW[i] = eW[i];   // stride loop: all 448 weights staged
    if (t < 64) sb[t] = eb[t];
    if (t < 3) { sm[t] = dmean[t]; sd[t] = dstd[t]; }
    __syncthreads();
    int lane = t & 63, wv = t >> 6;
    int w = blockIdx.x * 4 + wv, nw = gridDim.x * 4;
    for (int n = w; n < NN; n += nw) {
        float row[7];
#pragma unroll
        for (int k = 0; k < 7; k++) row[k] = nodes[n * 7 + k];
        if (isb[n]) {
#pragma unroll
            for (int k = 0; k < 3; k++) row[3 + k] = (row[3 + k] - sm[k]) / sd[k];
        }
        float acc = sb[lane];
#pragma unroll
        for (int k = 0; k < 7; k++) acc += row[k] * sW[k * 64 + lane];
        x[n * 64 + lane] = acc;
    }
}

// ---- coords min/max (ordered-uint atomics) ----
__global__ __launch_bounds__(256) void k_minmax(const float* __restrict__ nodes, unsigned* __restrict__ mn_ord,
                                                unsigned* __restrict__ mx_ord) {
    int tid = blockIdx.x * 256 + threadIdx.x;
    int stride = gridDim.x * 256;
    float mn[3] = {INFINITY, INFINITY, INFINITY};
    float mx[3] = {-INFINITY, -INFINITY, -INFINITY};
    for (int n = tid; n < NN; n += stride) {
#pragma unroll
        for (int k = 0; k < 3; k++) {
            float c = nodes[n * 7 + k];
            mn[k] = fminf(mn[k], c);
            mx[k] = fmaxf(mx[k], c);
        }
    }
#pragma unroll
    for (int off = 32; off; off >>= 1) {
#pragma unroll
        for (int k = 0; k < 3; k++) {
            mn[k] = fminf(mn[k], __shfl_down(mn[k], off));
            mx[k] = fmaxf(mx[k], __shfl_down(mx[k], off));
        }
    }
    if ((threadIdx.x & 63) == 0) {
#pragma unroll
        for (int k = 0; k < 3; k++) {
            atomicMin(&mn_ord[k], f2ord(mn[k]));
            atomicMax(&mx_ord[k], f2ord(mx[k]));
        }
    }
}

// ---- voxel block id per node ----
__global__ __launch_bounds__(256) void k_bid(const float* __restrict__ nodes, const unsigned* __restrict__ mn_ord,
                                             const unsigned* __restrict__ mx_ord, int* __restrict__ bid) {
    int n = blockIdx.x * 256 + threadIdx.x;
    if (n >= NN) return;
    int g[3];
#pragma unroll
    for (int k = 0; k < 3; k++) {
        float mn = ord2f(mn_ord[k]), mx = ord2f(mx_ord[k]);
        float cell = (mx - mn) / 8.0f;
        int gi = (int)floorf((nodes[n * 7 + k] - mn) / cell);
        gi = gi < 0 ? 0 : (gi > 7 ? 7 : gi);
        g[k] = gi;
    }
    bid[n] = g[0] * 64 + g[1] * 8 + g[2];
}

// ---- generic: h = x@W; a_s = h·A[:64]; a_r = h·A[64:]  (wave per row) ----
__global__ __launch_bounds__(256) void k_mm(const float* __restrict__ x, const float* __restrict__ W,
                                            const float* __restrict__ A, float* __restrict__ h,
                                            float* __restrict__ as_, float* __restrict__ ar_, int nrow) {
    __shared__ float sW[4096];
    __shared__ float sA[128];
    int t = threadIdx.x;
    for (int i = t; i < 4096; i += 256) sW[i] = W[i];
    if (t < 128) sA[t] = A[t];
    __syncthreads();
    int lane = t & 63, wv = t >> 6;
    int w = blockIdx.x * 4 + wv, nw = gridDim.x * 4;
    for (int n = w; n < nrow; n += nw) {
        const float* xr = x + (size_t)n * 64;
        float acc = 0.f;
#pragma unroll
        for (int k = 0; k < 64; k++) acc += xr[k] * sW[k * 64 + lane];
        h[(size_t)n * 64 + lane] = acc;
        float va = acc * sA[lane], vr = acc * sA[64 + lane];
#pragma unroll
        for (int off = 32; off; off >>= 1) {
            va += __shfl_down(va, off);
            vr += __shfl_down(vr, off);
        }
        if (lane == 0) { as_[n] = va; ar_[n] = vr; }
    }
}

// ---- fine GAT edge passes ----
__global__ __launch_bounds__(256) void k_edgeA(const int* __restrict__ se, const int* __restrict__ re,
                                               const float* __restrict__ as_, const float* __restrict__ ar_,
                                               unsigned* __restrict__ m_ord) {
    int e = blockIdx.x * 256 + threadIdx.x;
    if (e >= NE) return;
    float sc = lrelu(as_[se[e]] + ar_[re[e]]);
    atomicMax(&m_ord[re[e]], f2ord(sc));
}

__global__ __launch_bounds__(256) void k_edgeB(const int* __restrict__ se, const int* __restrict__ re,
                                               const float* __restrict__ as_, const float* __restrict__ ar_,
                                               const unsigned* __restrict__ m_ord, float* __restrict__ ssum) {
    int e = blockIdx.x * 256 + threadIdx.x;
    if (e >= NE) return;
    int r = re[e];
    float sc = lrelu(as_[se[e]] + ar_[r]);
    float w = __expf(sc - ord2f(m_ord[r]));
    unsafeAtomicAdd(&ssum[r], w);
}

// wave per edge: out_raw[r][lane] += w * h[s][lane]
__global__ __launch_bounds__(256) void k_edgeC(const int* __restrict__ se, const int* __restrict__ re,
                                               const float* __restrict__ as_, const float* __restrict__ ar_,
                                               const unsigned* __restrict__ m_ord, const float* __restrict__ h,
                                               float* __restrict__ o_raw) {
    int t = threadIdx.x, lane = t & 63;
    int e = blockIdx.x * 4 + (t >> 6);
    if (e >= NE) return;
    int s = se[e], r = re[e];
    float sc = lrelu(as_[s] + ar_[r]);
    float w = __expf(sc - ord2f(m_ord[r]));
    unsafeAtomicAdd(&o_raw[(size_t)r * 64 + lane], w * h[(size_t)s * 64 + lane]);
}

// ---- normalize by ssum (in place) + per-feature sum/sumsq partials ----
__global__ __launch_bounds__(256) void k_stats(float* __restrict__ o_raw, const float* __restrict__ ssum,
                                               float* __restrict__ colsum, float* __restrict__ colsq) {
    __shared__ float l1[4][64], l2[4][64];
    int t = threadIdx.x, lane = t & 63, wv = t >> 6;
    int w = blockIdx.x * 4 + wv, nw = gridDim.x * 4;
    float cs = 0.f, cq = 0.f;
    for (int n = w; n < NN; n += nw) {
        float ss = ssum[n];
        float v = o_raw[(size_t)n * 64 + lane];
        v = ss > 0.f ? v / ss : 0.f;
        o_raw[(size_t)n * 64 + lane] = v;
        cs += v;
        cq += v * v;
    }
    l1[wv][lane] = cs;
    l2[wv][lane] = cq;
    __syncthreads();
    if (wv == 0) {
        float a = l1[0][lane] + l1[1][lane] + l1[2][lane] + l1[3][lane];
        float b = l2[0][lane] + l2[1][lane] + l2[2][lane] + l2[3][lane];
        unsafeAtomicAdd(&colsum[lane], a);
        unsafeAtomicAdd(&colsq[lane], b);
    }
}

__global__ void k_meanvar(const float* __restrict__ colsum, const float* __restrict__ colsq, float* __restrict__ mr) {
    int t = threadIdx.x;
    if (t < 64) {
        float mean = colsum[t] / (float)NN;
        float var = colsq[t] / (float)NN - mean * mean;
        mr[t] = mean;
        mr[64 + t] = rsqrtf(var + 1e-5f);
    }
}

// ---- graphnorm + silu + res1; fused cnodes/segment-size accumulation ----
__global__ __launch_bounds__(256) void k_apply(const float* __restrict__ o_raw, const float* __restrict__ res1,
                                               const float* __restrict__ gamma, const float* __restrict__ beta,
                                               const float* __restrict__ mr, const int* __restrict__ bid,
                                               float* __restrict__ x1, float* __restrict__ cn,
                                               float* __restrict__ bsize) {
    int t = threadIdx.x, lane = t & 63;
    int n = blockIdx.x * 4 + (t >> 6);
    if (n >= NN) return;
    float v = o_raw[(size_t)n * 64 + lane];
    float y = gamma[lane] * (v - mr[lane]) * mr[64 + lane] + beta[lane];
    float s = y / (1.f + __expf(-y));
    float o = s + res1[(size_t)n * 64 + lane];
    x1[(size_t)n * 64 + lane] = o;
    int b = bid[n];
    unsafeAtomicAdd(&cn[b * 64 + lane], o);
    if (lane == 0) unsafeAtomicAdd(&bsize[b], 1.f);
}

// ---- coarse edge-count matrix ----
__global__ __launch_bounds__(256) void k_cnt(const int* __restrict__ se, const int* __restrict__ re,
                                             const int* __restrict__ bid, unsigned* __restrict__ cnt) {
    int e = blockIdx.x * 256 + threadIdx.x;
    if (e >= NE) return;
    atomicAdd(&cnt[bid[se[e]] * NCOARSE + bid[re[e]]], 1u);
}

// ---- cnodes scale: x2 = cn / sqrt(size + 1e-10) ----
__global__ __launch_bounds__(256) void k_cnscale(const float* __restrict__ cn, const float* __restrict__ bsize,
                                                 float* __restrict__ x2) {
    int t = threadIdx.x, lane = t & 63;
    int b = blockIdx.x * 4 + (t >> 6);
    if (b >= NCOARSE) return;
    x2[b * 64 + lane] = cn[b * 64 + lane] / sqrtf(bsize[b] + 1e-10f);
}

// ---- dense coarse GAT via count matrix (wave per receiver j) ----
__global__ __launch_bounds__(256) void k_cgat(const float* __restrict__ h, const float* __restrict__ as_,
                                              const float* __restrict__ ar_, const unsigned* __restrict__ cnt,
                                              float* __restrict__ g) {
    __shared__ float sa[NCOARSE];
    int t = threadIdx.x;
    for (int i = t; i < NCOARSE; i += 256) sa[i] = as_[i];
    __syncthreads();
    int lane = t & 63, wv = t >> 6;
    int j = blockIdx.x * 4 + wv;
    float arj = ar_[j];
    float m = -INFINITY;
    for (int i = 0; i < NCOARSE; i++) {
        if (cnt[i * NCOARSE + j]) m = fmaxf(m, lrelu(sa[i] + arj));
    }
    float ss = 0.f, acc = 0.f;
    for (int i = 0; i < NCOARSE; i++) {
        unsigned c = cnt[i * NCOARSE + j];
        if (c) {
            float w = (float)c * __expf(lrelu(sa[i] + arj) - m);
            ss += w;
            acc += w * h[i * 64 + lane];
        }
    }
    g[j * 64 + lane] = ss > 0.f ? acc / ss : 0.f;
}

// ---- coarse graphnorm + silu + residual (wave per feature) ----
__global__ __launch_bounds__(64) void k_cnorm(const float* __restrict__ gin, const float* __restrict__ gamma,
                                              const float* __restrict__ beta, const float* __restrict__ res,
                                              float* __restrict__ xout) {
    int f = blockIdx.x, lane = threadIdx.x;
    float v[8];
    float s = 0.f, q = 0.f;
#pragma unroll
    for (int k = 0; k < 8; k++) {
        v[k] = gin[(lane + 64 * k) * 64 + f];
        s += v[k];
        q += v[k] * v[k];
    }
#pragma unroll
    for (int off = 32; off; off >>= 1) {
        s += __shfl_down(s, off);
        q += __shfl_down(q, off);
    }
    s = __shfl(s, 0);
    q = __shfl(q, 0);
    float mean = s / 512.f, var = q / 512.f - mean * mean, rstd = rsqrtf(var + 1e-5f);
    float gf = gamma[f], bf = beta[f];
#pragma unroll
    for (int k = 0; k < 8; k++) {
        float y = gf * (v[k] - mean) * rstd + bf;
        float si = y / (1.f + __expf(-y));
        int idx = (lane + 64 * k) * 64 + f;
        xout[idx] = si + res[idx];
    }
}

// ---- final: out = sum_n sum_f (g3+x3)[n][f] * dW[f] + db ----
__global__ __launch_bounds__(256) void k_final(const float* __restrict__ g3, const float* __restrict__ x3,
                                               const float* __restrict__ dW, const float* __restrict__ db,
                                               float* __restrict__ out) {
    __shared__ float l[4];
    int t = threadIdx.x;
    float p = 0.f;
    for (int idx = t; idx < NCOARSE * 64; idx += 256) p += (g3[idx] + x3[idx]) * dW[idx & 63];
#pragma unroll
    for (int off = 32; off; off >>= 1) p += __shfl_down(p, off);
    if ((t & 63) == 0) l[t >> 6] = p;
    __syncthreads();
    if (t == 0) out[0] = l[0] + l[1] + l[2] + l[3] + db[0];
}

extern "C" void kernel_launch(void* const* d_in, const int* in_sizes, int n_in,
                              void* d_out, int out_size, void* d_ws, size_t ws_size,
                              hipStream_t stream) {
    const float* nodes = (const float*)d_in[0];
    const int* senders = (const int*)d_in[1];
    const int* receivers = (const int*)d_in[2];
    const int* bnodes = (const int*)d_in[3];
    const float* dmean = (const float*)d_in[4];
    const float* dstd = (const float*)d_in[5];
    const float* eW = (const float*)d_in[6];
    const float* eb = (const float*)d_in[7];
    const float* W1 = (const float*)d_in[8];
    const float* A1 = (const float*)d_in[9];
    const float* gamma1 = (const float*)d_in[10];
    const float* beta1 = (const float*)d_in[11];
    const float* W2 = (const float*)d_in[12];
    const float* A2 = (const float*)d_in[13];
    const float* gamma2 = (const float*)d_in[14];
    const float* beta2 = (const float*)d_in[15];
    const float* W3 = (const float*)d_in[16];
    const float* A3 = (const float*)d_in[17];
    const float* dW = (const float*)d_in[18];
    const float* db = (const float*)d_in[19];
    float* out = (float*)d_out;

    char* p = (char*)d_ws;
    auto alloc = [&](size_t b) { char* r = p; p += (b + 255) & ~(size_t)255; return r; };
    float* x_emb = (float*)alloc((size_t)NN * 64 * 4);   // res1
    float* h1 = (float*)alloc((size_t)NN * 64 * 4);      // reused as x1 after edgeC
    float* o_raw = (float*)alloc((size_t)NN * 64 * 4);
    float* as1 = (float*)alloc(NN * 4);
    float* ar1 = (float*)alloc(NN * 4);
    unsigned* m_ord = (unsigned*)alloc(NN * 4);
    float* ssum = (float*)alloc(NN * 4);
    int* bid = (int*)alloc(NN * 4);
    unsigned char* isb = (unsigned char*)alloc(NN);
    float* colsum = (float*)alloc(64 * 4);
    float* colsq = (float*)alloc(64 * 4);
    float* mr = (float*)alloc(128 * 4);
    unsigned* mn_ord = (unsigned*)alloc(3 * 4);
    unsigned* mx_ord = (unsigned*)alloc(3 * 4);
    unsigned* cnt = (unsigned*)alloc((size_t)NCOARSE * NCOARSE * 4);
    float* cn = (float*)alloc(NCOARSE * 64 * 4);
    float* bsize = (float*)alloc(NCOARSE * 4);
    float* x2 = (float*)alloc(NCOARSE * 64 * 4);   // res2
    float* h2 = (float*)alloc(NCOARSE * 64 * 4);
    float* as2 = (float*)alloc(NCOARSE * 4);
    float* ar2 = (float*)alloc(NCOARSE * 4);
    float* gat2 = (float*)alloc(NCOARSE * 64 * 4);
    float* x3 = (float*)alloc(NCOARSE * 64 * 4);   // res3
    float* h3 = (float*)alloc(NCOARSE * 64 * 4);
    float* as3 = (float*)alloc(NCOARSE * 4);
    float* ar3 = (float*)alloc(NCOARSE * 4);
    float* gat3 = (float*)alloc(NCOARSE * 64 * 4);

    hipMemsetAsync(m_ord, 0, NN * 4, stream);            // ord 0 == below all reals
    hipMemsetAsync(ssum, 0, NN * 4, stream);
    hipMemsetAsync(o_raw, 0, (size_t)NN * 64 * 4, stream);
    hipMemsetAsync(isb, 0, NN, stream);
    hipMemsetAsync(colsum, 0, 64 * 4, stream);
    hipMemsetAsync(colsq, 0, 64 * 4, stream);
    hipMemsetAsync(mn_ord, 0xFF, 12, stream);
    hipMemsetAsync(mx_ord, 0, 12, stream);
    hipMemsetAsync(cnt, 0, (size_t)NCOARSE * NCOARSE * 4, stream);
    hipMemsetAsync(cn, 0, NCOARSE * 64 * 4, stream);
    hipMemsetAsync(bsize, 0, NCOARSE * 4, stream);

    k_scatter<<<(NBN + 255) / 256, 256, 0, stream>>>(bnodes, isb);
    k_embed<<<2048, 256, 0, stream>>>(nodes, isb, dmean, dstd, eW, eb, x_emb);
    k_minmax<<<512, 256, 0, stream>>>(nodes, mn_ord, mx_ord);
    k_bid<<<(NN + 255) / 256, 256, 0, stream>>>(nodes, mn_ord, mx_ord, bid);
    k_mm<<<2048, 256, 0, stream>>>(x_emb, W1, A1, h1, as1, ar1, NN);
    k_edgeA<<<(NE + 255) / 256, 256, 0, stream>>>(senders, receivers, as1, ar1, m_ord);
    k_edgeB<<<(NE + 255) / 256, 256, 0, stream>>>(senders, receivers, as1, ar1, m_ord, ssum);
    k_edgeC<<<NE / 4, 256, 0, stream>>>(senders, receivers, as1, ar1, m_ord, h1, o_raw);
    k_stats<<<512, 256, 0, stream>>>(o_raw, ssum, colsum, colsq);
    k_meanvar<<<1, 64, 0, stream>>>(colsum, colsq, mr);
    k_apply<<<NN / 4, 256, 0, stream>>>(o_raw, x_emb, gamma1, beta1, mr, bid, h1, cn, bsize);
    k_cnt<<<(NE + 255) / 256, 256, 0, stream>>>(senders, receivers, bid, cnt);
    k_cnscale<<<NCOARSE / 4, 256, 0, stream>>>(cn, bsize, x2);
    k_mm<<<NCOARSE / 4, 256, 0, stream>>>(x2, W2, A2, h2, as2, ar2, NCOARSE);
    k_cgat<<<NCOARSE / 4, 256, 0, stream>>>(h2, as2, ar2, cnt, gat2);
    k_cnorm<<<64, 64, 0, stream>>>(gat2, gamma2, beta2, x2, x3);
    k_mm<<<NCOARSE / 4, 256, 0, stream>>>(x3, W3, A3, h3, as3, ar3, NCOARSE);
    k_cgat<<<NCOARSE / 4, 256, 0, stream>>>(h3, as3, ar3, cnt, gat3);
    k_final<<<1, 256, 0, stream>>>(gat3, x3, dW, db, out);
}